// Round 8
// baseline (272.191 us; speedup 1.0000x reference)
//
#include <hip/hip_runtime.h>

typedef short bf16x8 __attribute__((ext_vector_type(8)));
typedef float f32x16 __attribute__((ext_vector_type(16)));
typedef unsigned short u16;
typedef u16 ushort8v __attribute__((ext_vector_type(8)));

// ---- constants ----
#define VOCAB 100000
#define EMB 300
#define SEQ 40
#define BATCH 8192
#define COUT 210
#define NBLK 5
#define KPOOL 38
#define DH 35
#define NCLS 35
#define PCOL 320            // padded w2v row: 300 real + 20 zero (16B-aligned rows)
#define NUSE 192            // only channels 0..189 feed the pool
#define BM 128              // 3.2 batches -> always spans exactly 4 batches
#define ER 168              // 4 x 42 padded embedding rows resident in LDS
#define NGR 120             // total K granules (3 kh x 40)

__device__ __forceinline__ u16 f2bf(float f) {
  unsigned u = __float_as_uint(f);
  unsigned r = 0x7FFFu + ((u >> 16) & 1u);
  return (u16)((u + r) >> 16);
}

__device__ __forceinline__ void gload_lds16(void* lds, const void* g) {
  __builtin_amdgcn_global_load_lds(
      (const __attribute__((address_space(1))) void*)g,
      (__attribute__((address_space(3))) void*)lds, 16, 0, 0);
}

// ---- kernel 1: w2v f32 [VOCAB][300] -> W bf16 [VOCAB+1][320]; row VOCAB = zeros ----
__global__ __launch_bounds__(256) void k_prepW(const float* __restrict__ w2v,
                                               u16* __restrict__ W) {
  int id = blockIdx.x * 256 + threadIdx.x;          // (VOCAB+1)*40 chunks of 8
  if (id >= (VOCAB + 1) * 40) return;
  int v = id / 40, e8 = id - v * 40;
  int e = e8 * 8;
  float vals[8] = {0.f, 0.f, 0.f, 0.f, 0.f, 0.f, 0.f, 0.f};
  if (v < VOCAB) {
    const float* src = w2v + (size_t)v * EMB + e;
    if (e <= 292) {
      float4 f0 = *(const float4*)src;
      float4 f1 = *(const float4*)(src + 4);
      vals[0] = f0.x; vals[1] = f0.y; vals[2] = f0.z; vals[3] = f0.w;
      vals[4] = f1.x; vals[5] = f1.y; vals[6] = f1.z; vals[7] = f1.w;
    } else if (e == 296) {
      float4 f0 = *(const float4*)src;               // 296..299
      vals[0] = f0.x; vals[1] = f0.y; vals[2] = f0.z; vals[3] = f0.w;
    }
  }
  ushort8v o;
#pragma unroll
  for (int j = 0; j < 8; ++j) o[j] = f2bf(vals[j]);
  *(ushort8v*)(W + (size_t)v * PCOL + e) = o;
}

// ---- kernel 2: conv_w [3][300][210] -> Btn bf16 [120 gran][192 col][8] (zero padded) ----
__global__ __launch_bounds__(256) void k_prepB(const float* __restrict__ convw,
                                               u16* __restrict__ Btn) {
  int id = blockIdx.x * 256 + threadIdx.x;          // 120*192 = 23040
  if (id >= NGR * NUSE) return;
  int gg = id / NUSE, col = id - gg * NUSE;
  ushort8v o;
#pragma unroll
  for (int j = 0; j < 8; ++j) {
    int k = gg * 8 + j;
    int kh = (k >= 640) ? 2 : (k >= 320 ? 1 : 0);
    int e = k - kh * PCOL;
    float v = (e < EMB) ? convw[(kh * EMB + e) * COUT + col] : 0.f;
    o[j] = f2bf(v);
  }
  *(ushort8v*)(Btn + (size_t)id * 8) = o;
}

// ---- kernel 3: fused gather + conv (3 shifted K=320 sub-GEMMs) + bias/relu/pool ----
// 32x32x16 MFMA. Block = BM=128 rows (4 batches), 512 threads = 8 waves as 4M x 2N;
// wave tile 32x96 -> acc[3] f32x16 (48 VGPR). E-tile (168 rows x 40 gran x 16B =
// 105KB LDS) staged ONCE by per-lane global_load_lds gather from W; main loop:
// 60 steps (K=16) of 1 ds_read_b128 + 3 B global->VGPR loads + 3 MFMA.
// No barriers in the loop; compiler-inserted lgkmcnt/vmcnt handle deps.
__global__ __launch_bounds__(512) void k_conv_gemm(const u16* __restrict__ Wb,
                                                   const u16* __restrict__ Btn,
                                                   const int* __restrict__ x,
                                                   const float* __restrict__ convb,
                                                   float* __restrict__ maxc) {
  __shared__ __align__(16) char smem[40 * ER * 16];   // 107,520 B; epilogue aliases act
  float* act = (float*)smem;                           // [32][194]

  const int tid = threadIdx.x;
  const int lane = tid & 63;
  const int w = tid >> 6;
  const int wm = w >> 1, wn = w & 1;                  // 4M x 2N wave grid
  const int l31 = lane & 31, h = lane >> 5;
  const int m0 = blockIdx.x * BM;
  const int blo = m0 / SEQ;                           // first batch (block spans blo..blo+3)

  // ---- prologue: gather E-tile, chunk c=(g*ER+prow) at LDS c*16, 6720 chunks ----
#pragma unroll
  for (int ri = 0; ri < 13; ++ri) {
    const int c = ri * 512 + tid;                     // 0..6655
    const int g = c / ER, prow = c - g * ER;
    const int bb = prow / 42, sp = prow - bb * 42;
    const int tok = (sp == 0 || sp == 41) ? VOCAB : x[(blo + bb) * SEQ + sp - 1];
    gload_lds16(smem + c * 16, Wb + (size_t)tok * PCOL + g * 8);
  }
  if (tid < 64) {                                     // 6656..6719
    const int c = 6656 + tid;
    const int g = c / ER, prow = c - g * ER;
    const int bb = prow / 42, sp = prow - bb * 42;
    const int tok = (sp == 0 || sp == 41) ? VOCAB : x[(blo + bb) * SEQ + sp - 1];
    gload_lds16(smem + c * 16, Wb + (size_t)tok * PCOL + g * 8);
  }

  // ---- per-lane A base: row m = m0 + wm*32 + l31; prow(kh) = (b-blo)*42 + s + kh ----
  int aBase;
  {
    const int m = m0 + wm * 32 + l31;
    const int bA = m / SEQ, sA = m - bA * SEQ;
    aBase = ((h * ER) + (bA - blo) * 42 + sA) * 16;   // bytes; + ((2t%40)*ER + t/20)*16
  }
  // ---- per-lane B offset (elements): granule h, col = wn*96 + nf*32 + l31 ----
  const int bElem = (h * NUSE + wn * 96 + l31) * 8;

  f32x16 acc[3];
  const f32x16 zero16 = {0.f,0.f,0.f,0.f,0.f,0.f,0.f,0.f,0.f,0.f,0.f,0.f,0.f,0.f,0.f,0.f};
#pragma unroll
  for (int j = 0; j < 3; ++j) acc[j] = zero16;

  bf16x8 aR[2];
  bf16x8 bS[3][3];                                    // 3 rotating B sets

#define LOADA(SLOT, T)                                                         \
  aR[SLOT] = *(const bf16x8*)(smem + aBase + (((2 * (T)) % 40) * ER + (T) / 20) * 16);

#define LOADB(SI, T)                                                           \
  {                                                                            \
    const u16* p_ = Btn + (size_t)(T) * 3072 + bElem;                          \
    bS[SI][0] = *(const bf16x8*)(p_);                                          \
    bS[SI][1] = *(const bf16x8*)(p_ + 256);                                    \
    bS[SI][2] = *(const bf16x8*)(p_ + 512);                                    \
  }

  LOADB(0, 0)
  LOADB(1, 1)
  __syncthreads();                                    // E-tile resident (drains vmcnt)
  LOADA(0, 0)

#pragma unroll
  for (int t = 0; t < 60; ++t) {
    if (t + 1 < 60) { LOADA((t + 1) & 1, t + 1) }
    if (t + 2 < 60) { LOADB((t + 2) % 3, t + 2) }
    __builtin_amdgcn_s_setprio(1);
#pragma unroll
    for (int fn = 0; fn < 3; ++fn)
      acc[fn] = __builtin_amdgcn_mfma_f32_32x32x16_bf16(aR[t & 1], bS[t % 3][fn], acc[fn], 0, 0, 0);
    __builtin_amdgcn_s_setprio(0);
  }
#undef LOADA
#undef LOADB

  __syncthreads();                                    // E reads done -> act aliasing safe

  // ---- epilogue: 4 chunks of 32 rows (chunk ch = waves wm==ch); bias+relu -> LDS
  //      -> per-(row,group) max over 38 channels. All acc indices compile-time.
#pragma unroll
  for (int ch = 0; ch < 4; ++ch) {
    if (wm == ch) {
#pragma unroll
      for (int fn = 0; fn < 3; ++fn) {
        const int col = wn * 96 + fn * 32 + l31;      // < 192 < 210
        const float bias = convb[col];
#pragma unroll
        for (int r = 0; r < 16; ++r) {
          const int row = (r & 3) + 8 * (r >> 2) + 4 * h;   // verified C/D layout (m74/m101)
          act[row * 194 + col] = fmaxf(acc[fn][r] + bias, 0.f);
        }
      }
    }
    __syncthreads();
    if (tid < 160) {                                  // 32 rows x 5 groups
      const int rl = tid / 5, gq = tid - rl * 5;
      const float* ap = act + rl * 194 + gq * KPOOL;
      float mx = 0.f;                                 // relu => values >= 0
#pragma unroll
      for (int i = 0; i < KPOOL; ++i) mx = fmaxf(mx, ap[i]);
      const int m = m0 + ch * 32 + rl;
      const int bb = m / SEQ, ss = m - bb * SEQ;
      maxc[(bb * NBLK + gq) * SEQ + ss] = mx;         // unmasked max; mask applied in k_dense
    }
    __syncthreads();
  }
}

// ---- kernel 4: region-masked dense (120->35) + out (35->35) ----
__global__ __launch_bounds__(256) void k_dense(const float* __restrict__ maxc,
                                               const int* __restrict__ pos,
                                               const float* __restrict__ dw,
                                               const float* __restrict__ db,
                                               const float* __restrict__ ow,
                                               const float* __restrict__ ob,
                                               float* __restrict__ out) {
  __shared__ float dwL[120 * 36];
  __shared__ float owL[35 * 36];
  __shared__ float hL[64 * 36];
  __shared__ float mxL[64 * 40];
  const int tid = threadIdx.x;
  const int r0 = blockIdx.x * 64;                    // 640 blocks x 64 rows
  for (int i = tid; i < 120 * 35; i += 256) { int j = i / 35, d = i - j * 35; dwL[j * 36 + d] = dw[i]; }
  for (int i = tid; i < 35 * 35; i += 256)  { int j = i / 35, d = i - j * 35; owL[j * 36 + d] = ow[i]; }
  for (int i = tid; i < 64 * 40; i += 256)  mxL[i] = maxc[(size_t)r0 * 40 + i];
  __syncthreads();
  for (int t = tid; t < 64 * 35; t += 256) {
    const int row = t / 35, d = t - row * 35;
    const int rg = r0 + row;
    const int b = rg / NBLK;
    const int p0 = pos[b * 2], p1 = pos[b * 2 + 1];
    int e1 = min(p0, p1), e2 = max(p0, p1);
    if (e1 == 0) { e1 = 1; e2 += 1; }
    float a = db[d];
#pragma unroll
    for (int s = 0; s < SEQ; ++s) {
      const int k = (s >= e1) + (s >= e2);           // region of position s
      a += mxL[row * 40 + s] * dwL[(k * SEQ + s) * 36 + d];
    }
    hL[row * 36 + d] = a;
  }
  __syncthreads();
  for (int t = tid; t < 64 * 35; t += 256) {
    const int row = t / 35, c = t - row * 35;
    float a = ob[c];
#pragma unroll
    for (int d = 0; d < DH; ++d) a += hL[row * 36 + d] * owL[d * 36 + c];
    out[(size_t)(r0 + row) * NCLS + c] = a;
  }
}

extern "C" void kernel_launch(void* const* d_in, const int* in_sizes, int n_in,
                              void* d_out, int out_size, void* d_ws, size_t ws_size,
                              hipStream_t stream) {
  const int*   x     = (const int*)d_in[0];
  const int*   pos   = (const int*)d_in[1];
  const float* w2v   = (const float*)d_in[2];
  const float* convw = (const float*)d_in[3];
  const float* convb = (const float*)d_in[4];
  const float* dw    = (const float*)d_in[5];
  const float* db    = (const float*)d_in[6];
  const float* ow    = (const float*)d_in[7];
  const float* ob    = (const float*)d_in[8];
  float* out = (float*)d_out;

  char* ws = (char*)d_ws;
  u16* W    = (u16*)ws;                               // (100001)*320*2 = 64,000,640 B
  u16* Btn  = (u16*)(ws + 64000640);                  // 120*192*8*2   =    368,640 B
  float* maxc = (float*)(ws + 64000640 + 368640);     // 40960*40*4    =  6,553,600 B

  k_prepW<<<15626, 256, 0, stream>>>(w2v, W);         // (100001*40+255)/256
  k_prepB<<<90, 256, 0, stream>>>(convw, Btn);        // 23040/256
  k_conv_gemm<<<2560, 512, 0, stream>>>(W, Btn, x, convb, maxc);  // 327680/128
  k_dense<<<640, 256, 0, stream>>>(maxc, pos, dw, db, ow, ob, out);
}